// Round 1
// baseline (3767.403 us; speedup 1.0000x reference)
//
#include <hip/hip_runtime.h>
#include <math.h>

#define HID 64

__global__ void zero_kernel(float* __restrict__ p, int n) {
    int i = blockIdx.x * blockDim.x + threadIdx.x;
    int stride = gridDim.x * blockDim.x;
    for (; i < n; i += stride) p[i] = 0.f;
}

__global__ void count_kernel(const int* __restrict__ eidx, float* __restrict__ cnt, int E) {
    int i = blockIdx.x * blockDim.x + threadIdx.x;
    if (i < E) atomicAdd(&cnt[eidx[E + i]], 1.0f);
}

// first encoder layer: Y[n,j] = relu(b[j] + sum_{k<5} NF[n,k]*W[k,j])
__global__ __launch_bounds__(256)
void enc1_kernel(const float* __restrict__ NF, const float* __restrict__ W,
                 const float* __restrict__ b, float* __restrict__ Y, int N) {
    int lane = threadIdx.x & 63;
    float w0 = W[0 * 64 + lane], w1 = W[1 * 64 + lane], w2 = W[2 * 64 + lane];
    float w3 = W[3 * 64 + lane], w4 = W[4 * 64 + lane];
    float bv = b[lane];
    int wid = (blockIdx.x * blockDim.x + threadIdx.x) >> 6;
    int nw = (gridDim.x * blockDim.x) >> 6;
    for (int n = wid; n < N; n += nw) {
        float x = (lane < 5) ? NF[n * 5 + lane] : 0.f;
        float acc = bv;
        acc = fmaf(__shfl(x, 0), w0, acc);
        acc = fmaf(__shfl(x, 1), w1, acc);
        acc = fmaf(__shfl(x, 2), w2, acc);
        acc = fmaf(__shfl(x, 3), w3, acc);
        acc = fmaf(__shfl(x, 4), w4, acc);
        Y[n * 64 + lane] = fmaxf(acc, 0.f);
    }
}

// Y[n,j] = (relu?)(b[j] + sum_k X[n,k]*W[k,j]), K = 64
__global__ __launch_bounds__(256, 2)
void gemm64_kernel(const float* __restrict__ X, const float* __restrict__ W,
                   const float* __restrict__ b, float* __restrict__ Y,
                   int N, int doRelu) {
    int lane = threadIdx.x & 63;
    float wcol[64];
#pragma unroll
    for (int k = 0; k < 64; ++k) wcol[k] = W[k * 64 + lane];
    float bv = b[lane];
    int wid = (blockIdx.x * blockDim.x + threadIdx.x) >> 6;
    int nw = (gridDim.x * blockDim.x) >> 6;
    for (int n = wid; n < N; n += nw) {
        float x = X[n * 64 + lane];
        float acc = bv;
#pragma unroll
        for (int k = 0; k < 64; ++k) acc = fmaf(__shfl(x, k), wcol[k], acc);
        if (doRelu) acc = fmaxf(acc, 0.f);
        Y[n * 64 + lane] = acc;
    }
}

// fused message + scatter:
// per edge e: eh = relu(f*eW + eB); hid = relu(G[src] + eh@W1b);
//             m = relu(hid@W2 + b2); atomicAdd(Agg[dst], m)
// (G already includes h@W1a + b1)
__global__ __launch_bounds__(256, 2)
void msg_kernel(const float* __restrict__ G, const float* __restrict__ EF,
                const int* __restrict__ EI, const float* __restrict__ eW,
                const float* __restrict__ eB, const float* __restrict__ W1b,
                const float* __restrict__ W2, const float* __restrict__ b2,
                float* __restrict__ Agg, int E) {
    int lane = threadIdx.x & 63;
    float w1c[64], w2c[64];
#pragma unroll
    for (int k = 0; k < 64; ++k) w1c[k] = W1b[k * 64 + lane];
#pragma unroll
    for (int k = 0; k < 64; ++k) w2c[k] = W2[k * 64 + lane];
    float ew = eW[lane], ebv = eB[lane], b2v = b2[lane];
    int wid = (blockIdx.x * blockDim.x + threadIdx.x) >> 6;
    int nw = (gridDim.x * blockDim.x) >> 6;
    for (int e = wid; e < E; e += nw) {
        float f = EF[e];
        int src = EI[e];
        int dst = EI[E + e];
        float ehv = fmaxf(fmaf(f, ew, ebv), 0.f);
        float ce = 0.f;
#pragma unroll
        for (int k = 0; k < 64; ++k) ce = fmaf(__shfl(ehv, k), w1c[k], ce);
        float hid = fmaxf(G[(size_t)src * 64 + lane] + ce, 0.f);
        float m = b2v;
#pragma unroll
        for (int k = 0; k < 64; ++k) m = fmaf(__shfl(hid, k), w2c[k], m);
        m = fmaxf(m, 0.f);
        atomicAdd(&Agg[(size_t)dst * 64 + lane], m);
    }
}

// update layer 1: Y[n,j] = relu(b1[j] + sum_k Hc[n,k]*U1[k,j] + sum_k (Agg[n,k]/max(cnt,1))*U1[64+k,j])
__global__ __launch_bounds__(256, 2)
void upd1_kernel(const float* __restrict__ Hc, const float* __restrict__ Agg,
                 const float* __restrict__ cnt, const float* __restrict__ U1,
                 const float* __restrict__ b1, float* __restrict__ Y, int N) {
    int lane = threadIdx.x & 63;
    float ua[64], ub[64];
#pragma unroll
    for (int k = 0; k < 64; ++k) ua[k] = U1[k * 64 + lane];
#pragma unroll
    for (int k = 0; k < 64; ++k) ub[k] = U1[(64 + k) * 64 + lane];
    float bv = b1[lane];
    int wid = (blockIdx.x * blockDim.x + threadIdx.x) >> 6;
    int nw = (gridDim.x * blockDim.x) >> 6;
    for (int n = wid; n < N; n += nw) {
        float x = Hc[n * 64 + lane];
        float inv = 1.f / fmaxf(cnt[n], 1.f);
        float a = Agg[n * 64 + lane] * inv;
        float acc = bv;
#pragma unroll
        for (int k = 0; k < 64; ++k) acc = fmaf(__shfl(x, k), ua[k], acc);
#pragma unroll
        for (int k = 0; k < 64; ++k) acc = fmaf(__shfl(a, k), ub[k], acc);
        Y[n * 64 + lane] = fmaxf(acc, 0.f);
    }
}

// head: t = relu(Hc@W1 + b1); pred[c] = sum_j t[j]*W2[j,c] + b2[c]; out = 2pi*sigmoid(pred)
__global__ __launch_bounds__(256, 2)
void head_kernel(const float* __restrict__ Hc, const float* __restrict__ W1,
                 const float* __restrict__ b1, const float* __restrict__ W2,
                 const float* __restrict__ b2, float* __restrict__ out, int N) {
    int lane = threadIdx.x & 63;
    float wcol[64];
#pragma unroll
    for (int k = 0; k < 64; ++k) wcol[k] = W1[k * 64 + lane];
    float bv = b1[lane];
    float w2c0 = W2[lane * 3 + 0], w2c1 = W2[lane * 3 + 1], w2c2 = W2[lane * 3 + 2];
    float b20 = b2[0], b21 = b2[1], b22 = b2[2];
    int wid = (blockIdx.x * blockDim.x + threadIdx.x) >> 6;
    int nw = (gridDim.x * blockDim.x) >> 6;
    const float TWO_PI = 6.283185307179586f;
    for (int n = wid; n < N; n += nw) {
        float x = Hc[n * 64 + lane];
        float t = bv;
#pragma unroll
        for (int k = 0; k < 64; ++k) t = fmaf(__shfl(x, k), wcol[k], t);
        t = fmaxf(t, 0.f);
        float p0 = t * w2c0, p1 = t * w2c1, p2 = t * w2c2;
#pragma unroll
        for (int off = 32; off > 0; off >>= 1) {
            p0 += __shfl_xor(p0, off);
            p1 += __shfl_xor(p1, off);
            p2 += __shfl_xor(p2, off);
        }
        if (lane == 0) {
            float v0 = p0 + b20, v1 = p1 + b21, v2 = p2 + b22;
            out[n * 3 + 0] = TWO_PI / (1.f + expf(-v0));
            out[n * 3 + 1] = TWO_PI / (1.f + expf(-v1));
            out[n * 3 + 2] = TWO_PI / (1.f + expf(-v2));
        }
    }
}

extern "C" void kernel_launch(void* const* d_in, const int* in_sizes, int n_in,
                              void* d_out, int out_size, void* d_ws, size_t ws_size,
                              hipStream_t stream) {
    const float* nf    = (const float*)d_in[0];
    const int*   ei    = (const int*)d_in[1];
    const float* ef    = (const float*)d_in[2];
    const float* encW1 = (const float*)d_in[3];
    const float* encb1 = (const float*)d_in[4];
    const float* encW2 = (const float*)d_in[5];
    const float* encb2 = (const float*)d_in[6];
    const float* eeW   = (const float*)d_in[7];
    const float* eeb   = (const float*)d_in[8];
    const float* mW1   = (const float*)d_in[9];
    const float* mb1   = (const float*)d_in[10];
    const float* mW2   = (const float*)d_in[11];
    const float* mb2   = (const float*)d_in[12];
    const float* uW1   = (const float*)d_in[13];
    const float* ub1   = (const float*)d_in[14];
    const float* uW2   = (const float*)d_in[15];
    const float* ub2   = (const float*)d_in[16];
    const float* oW1   = (const float*)d_in[17];
    const float* ob1   = (const float*)d_in[18];
    const float* oW2   = (const float*)d_in[19];
    const float* ob2   = (const float*)d_in[20];
    float* out = (float*)d_out;

    int N = in_sizes[0] / 5;   // 50000
    int E = in_sizes[2];       // 800000

    float* ws  = (float*)d_ws;
    float* h   = ws;
    float* hn  = ws + (size_t)N * 64;
    float* g   = ws + (size_t)2 * N * 64;
    float* agg = ws + (size_t)3 * N * 64;
    float* cnt = ws + (size_t)4 * N * 64;

    // node encoder
    enc1_kernel<<<512, 256, 0, stream>>>(nf, encW1, encb1, g, N);
    gemm64_kernel<<<1024, 256, 0, stream>>>(g, encW2, encb2, h, N, 1);

    // in-degree counts
    zero_kernel<<<256, 256, 0, stream>>>(cnt, N);
    count_kernel<<<(E + 255) / 256, 256, 0, stream>>>(ei, cnt, E);

    for (int l = 0; l < 3; ++l) {
        const float* W1a = mW1 + (size_t)l * 128 * 64;
        const float* W1b = W1a + 64 * 64;
        const float* b1  = mb1 + l * 64;
        const float* W2  = mW2 + (size_t)l * 64 * 64;
        const float* b2  = mb2 + l * 64;
        // g = h @ W1a + b1   (src-side half of the concat matmul, per node)
        gemm64_kernel<<<1024, 256, 0, stream>>>(h, W1a, b1, g, N, 0);
        zero_kernel<<<1024, 256, 0, stream>>>(agg, N * 64);
        msg_kernel<<<2048, 256, 0, stream>>>(g, ef, ei, eeW, eeb, W1b, W2, b2, agg, E);

        const float* U1 = uW1 + (size_t)l * 128 * 64;
        const float* v1 = ub1 + l * 64;
        const float* U2 = uW2 + (size_t)l * 64 * 64;
        const float* v2 = ub2 + l * 64;
        upd1_kernel<<<1024, 256, 0, stream>>>(h, agg, cnt, U1, v1, g, N);
        gemm64_kernel<<<1024, 256, 0, stream>>>(g, U2, v2, hn, N, 1);
        float* tmp = h; h = hn; hn = tmp;
    }

    head_kernel<<<1024, 256, 0, stream>>>(h, oW1, ob1, oW2, ob2, out, N);
}